// Round 7
// baseline (411.340 us; speedup 1.0000x reference)
//
#include <hip/hip_runtime.h>
#include <hip/hip_bf16.h>

// GIN forward, MI355X. Separate agg (proven 3.66TB/s) + single-pass barrier-free
// MFMA GEMMs: B panel LDS-resident (pre-swizzled weights, linear stage),
// A fragments global->reg all-K-upfront, one barrier, LDS-staged C.

#define NN 50000
#define EE 800000
#define FDIM 128
#define HDIM 256
#define CDIM 40
#define BN_EPS 1e-5f

typedef unsigned short u16;
typedef unsigned int u32;
typedef __attribute__((ext_vector_type(8))) short short8;
typedef __attribute__((ext_vector_type(4))) float f32x4;

__device__ __forceinline__ float bflo(u32 u) { return __uint_as_float(u << 16); }
__device__ __forceinline__ float bfhi(u32 u) { return __uint_as_float(u & 0xFFFF0000u); }
__device__ __forceinline__ u16 f2bf(float f) {
  __hip_bfloat16 h = __float2bfloat16(f);
  return *(u16*)&h;
}
__device__ __forceinline__ u32 pack2(float a, float b) {
  return (u32)f2bf(a) | ((u32)f2bf(b) << 16);
}

// ---------------- CSR build ----------------
__global__ void k_hist(const int* __restrict__ ei, int* __restrict__ deg) {
  int e = blockIdx.x * 256 + threadIdx.x;
  if (e < EE) atomicAdd(&deg[ei[EE + e]], 1);
}

__global__ void k_scan_blocks(const int* __restrict__ in, int* __restrict__ partial,
                              int* __restrict__ bsums, int n) {
  __shared__ int s[256];
  int i = blockIdx.x * 256 + threadIdx.x;
  s[threadIdx.x] = (i < n) ? in[i] : 0;
  __syncthreads();
  for (int d = 1; d < 256; d <<= 1) {
    int t = (threadIdx.x >= d) ? s[threadIdx.x - d] : 0;
    __syncthreads();
    s[threadIdx.x] += t;
    __syncthreads();
  }
  if (i < n) partial[i] = s[threadIdx.x];
  if (threadIdx.x == 255) bsums[blockIdx.x] = s[255];
}

__global__ void k_scan_sums(int* __restrict__ bs, int nb) {
  __shared__ int s[256];
  s[threadIdx.x] = (threadIdx.x < nb) ? bs[threadIdx.x] : 0;
  __syncthreads();
  for (int d = 1; d < 256; d <<= 1) {
    int t = (threadIdx.x >= d) ? s[threadIdx.x - d] : 0;
    __syncthreads();
    s[threadIdx.x] += t;
    __syncthreads();
  }
  int ex = (threadIdx.x == 0) ? 0 : s[threadIdx.x - 1];
  if (threadIdx.x < nb) bs[threadIdx.x] = ex;
}

// writes rowstart[i+1] and cursor[i] = rowstart[i]
__global__ void k_scan_add(const int* __restrict__ partial, const int* __restrict__ bs,
                           const int* __restrict__ deg,
                           int* __restrict__ rowstart, int* __restrict__ cursor, int n) {
  int i = blockIdx.x * 256 + threadIdx.x;
  if (i < n) {
    int incl = partial[i] + bs[blockIdx.x];
    rowstart[i + 1] = incl;
    cursor[i] = incl - deg[i];
  }
  if (i == 0) rowstart[0] = 0;
}

__global__ void k_scatter(const int* __restrict__ ei, int* __restrict__ cursor,
                          int* __restrict__ sorted_src) {
  int e = blockIdx.x * 256 + threadIdx.x;
  if (e < EE) {
    int dst = ei[EE + e];
    int p = atomicAdd(&cursor[dst], 1);
    sorted_src[p] = ei[e];
  }
}

// ---------------- conversions ----------------
// x -> bf16 (normal layout); also zeroes deg and stats
__global__ void k_cvt_x(const float* __restrict__ x, u16* __restrict__ xb,
                        int* __restrict__ deg, float* __restrict__ stats) {
  int i = blockIdx.x * 256 + threadIdx.x;
  if (i < NN) deg[i] = 0;
  if (i < 6 * 256) stats[i] = 0.f;
  size_t base = (size_t)i * 4;
  if (base < (size_t)NN * FDIM) {
    float4 v = *(const float4*)&x[base];
    *(uint2*)&xb[base] = make_uint2(pack2(v.x, v.y), pack2(v.z, v.w));
  }
}

// weights: W[K,256] f32 -> Wt[256][K] bf16 with 16B-chunk XOR swizzle (ch ^ (col&7));
// Wf[256,40] -> Wft[48][256] padded, same swizzle.
__global__ void k_cvt_w(const float* __restrict__ W1, const float* __restrict__ W2,
                        const float* __restrict__ W3, const float* __restrict__ W4,
                        const float* __restrict__ Wf,
                        u16* __restrict__ W1t, u16* __restrict__ W2t,
                        u16* __restrict__ W3t, u16* __restrict__ W4t,
                        u16* __restrict__ Wft) {
  int b = blockIdx.x, t = threadIdx.x;
  if (b < 128) {
    int i = b * 256 + t; int k = i >> 8, n = i & 255;
    W1t[(size_t)n * 128 + (((k >> 3) ^ (n & 7)) << 3) + (k & 7)] = f2bf(W1[i]);
  } else if (b < 384) {
    int i = (b - 128) * 256 + t; int k = i >> 8, n = i & 255;
    W2t[(size_t)n * 256 + (((k >> 3) ^ (n & 7)) << 3) + (k & 7)] = f2bf(W2[i]);
  } else if (b < 640) {
    int i = (b - 384) * 256 + t; int k = i >> 8, n = i & 255;
    W3t[(size_t)n * 256 + (((k >> 3) ^ (n & 7)) << 3) + (k & 7)] = f2bf(W3[i]);
  } else if (b < 896) {
    int i = (b - 640) * 256 + t; int k = i >> 8, n = i & 255;
    W4t[(size_t)n * 256 + (((k >> 3) ^ (n & 7)) << 3) + (k & 7)] = f2bf(W4[i]);
  } else {
    int j = (b - 896) * 256 + t;        // dest-centric over [48][256]
    int c = j >> 8, k = j & 255;
    float v = (c < CDIM) ? Wf[(size_t)k * CDIM + c] : 0.f;
    Wft[(size_t)c * 256 + (((k >> 3) ^ (c & 7)) << 3) + (k & 7)] = f2bf(v);
  }
}

// ---------------- aggregation (bf16 in/out, f32 accumulate, 8-deep MLP) ----------------
template <int FEAT>
__global__ __launch_bounds__(256)
void k_agg(const u16* __restrict__ x, const int* __restrict__ rowstart,
           const int* __restrict__ sorted_src, const float* __restrict__ epsp,
           u16* __restrict__ out) {
  int node = blockIdx.x * 4 + (threadIdx.x >> 6);
  if (node >= NN) return;
  int lane = threadIdx.x & 63;
  float e1 = 1.0f + epsp[0];
  int s = rowstart[node], t = rowstart[node + 1];
  if constexpr (FEAT == 128) {
    const u32* xp = (const u32*)x;
    u32 u = xp[(size_t)node * 64 + lane];
    float a0 = bflo(u) * e1, a1 = bfhi(u) * e1;
    int p = s;
    for (; p + 7 < t; p += 8) {
      u32 uu[8];
#pragma unroll
      for (int i = 0; i < 8; ++i) uu[i] = xp[(size_t)sorted_src[p + i] * 64 + lane];
#pragma unroll
      for (int i = 0; i < 8; ++i) { a0 += bflo(uu[i]); a1 += bfhi(uu[i]); }
    }
    for (; p + 1 < t; p += 2) {
      u32 u0 = xp[(size_t)sorted_src[p] * 64 + lane];
      u32 u1 = xp[(size_t)sorted_src[p + 1] * 64 + lane];
      a0 += bflo(u0) + bflo(u1);
      a1 += bfhi(u0) + bfhi(u1);
    }
    if (p < t) {
      u32 u0 = xp[(size_t)sorted_src[p] * 64 + lane];
      a0 += bflo(u0); a1 += bfhi(u0);
    }
    ((u32*)out)[(size_t)node * 64 + lane] = pack2(a0, a1);
  } else {
    const uint2* xp = (const uint2*)x;
    uint2 u = xp[(size_t)node * 64 + lane];
    float a0 = bflo(u.x) * e1, a1 = bfhi(u.x) * e1;
    float a2 = bflo(u.y) * e1, a3 = bfhi(u.y) * e1;
    int p = s;
    for (; p + 7 < t; p += 8) {
      uint2 uu[8];
#pragma unroll
      for (int i = 0; i < 8; ++i) uu[i] = xp[(size_t)sorted_src[p + i] * 64 + lane];
#pragma unroll
      for (int i = 0; i < 8; ++i) {
        a0 += bflo(uu[i].x); a1 += bfhi(uu[i].x);
        a2 += bflo(uu[i].y); a3 += bfhi(uu[i].y);
      }
    }
    for (; p + 1 < t; p += 2) {
      uint2 u0 = xp[(size_t)sorted_src[p] * 64 + lane];
      uint2 u1 = xp[(size_t)sorted_src[p + 1] * 64 + lane];
      a0 += bflo(u0.x) + bflo(u1.x);
      a1 += bfhi(u0.x) + bfhi(u1.x);
      a2 += bflo(u0.y) + bflo(u1.y);
      a3 += bfhi(u0.y) + bfhi(u1.y);
    }
    if (p < t) {
      uint2 u0 = xp[(size_t)sorted_src[p] * 64 + lane];
      a0 += bflo(u0.x); a1 += bfhi(u0.x);
      a2 += bflo(u0.y); a3 += bfhi(u0.y);
    }
    ((uint2*)out)[(size_t)node * 64 + lane] = make_uint2(pack2(a0, a1), pack2(a2, a3));
  }
}

// ---------------- single-pass MFMA GEMM ----------------
// C[64-row tile, 256 cols] = opA(A[64,K]) @ Bt[256,K]^T + bias.
// 512 threads (8 waves: wm 0..1 x wn 0..3, wave = 32 rows x 64 cols).
// B panel (pre-swizzled) linear-staged to LDS; A frags global->reg, all K upfront;
// ONE barrier before MFMA; no barriers in K loop. C via 16KB LDS staging.
// opA = relu(z*a+c) from BN stats (TRANSFORM). Optional relu-out / colsums.
template <int K, bool TRANSFORM, bool RELU_OUT, bool COLSUMS>
__global__ __launch_bounds__(512)
void k_gemm(const u16* __restrict__ A, const u16* __restrict__ Bt,
            const float* __restrict__ bias,
            const float* __restrict__ icsum, const float* __restrict__ icsq,
            const float* __restrict__ g, const float* __restrict__ be,
            u16* __restrict__ C, float* __restrict__ ocsum, float* __restrict__ ocsq) {
  constexpr int NKS = K / 32;
  __shared__ u16 Bs[256 * K];            // 64/128 KB
  __shared__ u16 Cs[32 * 256];           // 16 KB
  __shared__ float2 Tb[TRANSFORM ? K : 1];

  const int tid = threadIdx.x;
  const int lane = tid & 63;
  const int w = tid >> 6;
  const int wm = w >> 2, wn = w & 3;
  const int lr = lane & 15, lq = lane >> 4;
  const int r0 = blockIdx.x * 64;

  // A fragments: 2 rows x NKS chunks, all in flight immediately
  short8 a[2][NKS];
#pragma unroll
  for (int mi = 0; mi < 2; ++mi) {
    int row = r0 + wm * 32 + mi * 16 + lr;
    int rc = row < NN ? row : NN - 1;
    const u16* Ap = &A[(size_t)rc * K];
#pragma unroll
    for (int ks = 0; ks < NKS; ++ks)
      a[mi][ks] = *(const short8*)&Ap[(ks * 4 + lq) * 8];
  }

  // B panel: linear copy (source already swizzled)
  {
    const short8* Bv = (const short8*)Bt;
    short8* Bl = (short8*)Bs;
#pragma unroll
    for (int i = 0; i < K / 16; ++i)
      Bl[tid + i * 512] = Bv[tid + i * 512];
  }
  if constexpr (TRANSFORM) {
    if (tid < 256) {
      float m = icsum[tid] * (1.0f / NN);
      float var = icsq[tid] * (1.0f / NN) - m * m;
      float s = g[tid] * rsqrtf(var + BN_EPS);
      Tb[tid] = make_float2(s, be[tid] - m * s);
    }
  }
  __syncthreads();

  f32x4 acc[2][4];
#pragma unroll
  for (int mi = 0; mi < 2; ++mi)
#pragma unroll
    for (int ni = 0; ni < 4; ++ni) acc[mi][ni] = (f32x4){0.f, 0.f, 0.f, 0.f};

#pragma unroll
  for (int ks = 0; ks < NKS; ++ks) {
    short8 am0, am1;
    if constexpr (TRANSFORM) {
      short8 t0 = a[0][ks], t1 = a[1][ks];
      int kb = (ks * 4 + lq) * 8;
#pragma unroll
      for (int j = 0; j < 8; ++j) {
        float2 tb = Tb[kb + j];
        float f0 = fmaxf(fmaf(__uint_as_float(((u32)(u16)t0[j]) << 16), tb.x, tb.y), 0.f);
        float f1 = fmaxf(fmaf(__uint_as_float(((u32)(u16)t1[j]) << 16), tb.x, tb.y), 0.f);
        t0[j] = (short)f2bf(f0);
        t1[j] = (short)f2bf(f1);
      }
      am0 = t0; am1 = t1;
    } else {
      am0 = a[0][ks]; am1 = a[1][ks];
    }
#pragma unroll
    for (int ni = 0; ni < 4; ++ni) {
      int col = wn * 64 + ni * 16 + lr;
      short8 bfr = *(const short8*)&Bs[(size_t)col * K + (((ks * 4 + lq) ^ (col & 7)) << 3)];
      acc[0][ni] = __builtin_amdgcn_mfma_f32_16x16x32_bf16(am0, bfr, acc[0][ni], 0, 0, 0);
      acc[1][ni] = __builtin_amdgcn_mfma_f32_16x16x32_bf16(am1, bfr, acc[1][ni], 0, 0, 0);
    }
  }

  float bv[4];
#pragma unroll
  for (int ni = 0; ni < 4; ++ni) bv[ni] = bias[wn * 64 + ni * 16 + lr];
  float colS[4] = {}, colQ[4] = {};

  // two 32-row epilogue rounds through Cs
#pragma unroll
  for (int r = 0; r < 2; ++r) {
    if (wm == r) {
#pragma unroll
      for (int mi = 0; mi < 2; ++mi)
#pragma unroll
        for (int ni = 0; ni < 4; ++ni) {
          int col = wn * 64 + ni * 16 + lr;
#pragma unroll
          for (int j = 0; j < 4; ++j) {
            int lrow = mi * 16 + lq * 4 + j;
            float v = acc[mi][ni][j] + bv[ni];
            if constexpr (RELU_OUT) v = fmaxf(v, 0.f);
            if constexpr (COLSUMS) {
              if (r0 + r * 32 + lrow < NN) { colS[ni] += v; colQ[ni] += v * v; }
            }
            Cs[lrow * 256 + col] = f2bf(v);
          }
        }
    }
    __syncthreads();
#pragma unroll
    for (int sub = 0; sub < 2; ++sub) {
      int lrow = sub * 16 + (tid >> 5);
      int gr = r0 + r * 32 + lrow;
      if (gr < NN)
        *(uint4*)&C[(size_t)gr * 256 + (tid & 31) * 8] =
            *(const uint4*)&Cs[lrow * 256 + (tid & 31) * 8];
    }
    __syncthreads();
  }

  if constexpr (COLSUMS) {
#pragma unroll
    for (int ni = 0; ni < 4; ++ni) {
      float s = colS[ni], q = colQ[ni];
      s += __shfl_xor(s, 16); s += __shfl_xor(s, 32);
      q += __shfl_xor(q, 16); q += __shfl_xor(q, 32);
      if (lq == 0) {
        int col = wn * 64 + ni * 16 + lr;
        atomicAdd(&ocsum[col], s);
        atomicAdd(&ocsq[col], q);
      }
    }
  }
}

// ---------------- final: out[N,40] = relu(bn3(z3)) @ Wf + bf (MFMA, 48-col pad) ----------------
__global__ __launch_bounds__(512)
void k_final(const u16* __restrict__ z3, const u16* __restrict__ Wft,
             const float* __restrict__ bfp,
             const float* __restrict__ icsum, const float* __restrict__ icsq,
             const float* __restrict__ g, const float* __restrict__ be,
             float* __restrict__ out) {
  __shared__ u16 Bs[48 * 256];
  __shared__ float2 Tb[256];
  const int tid = threadIdx.x;
  const int lane = tid & 63;
  const int w = tid >> 6;        // 0..7, 16 rows each
  const int lr = lane & 15, lq = lane >> 4;
  const int r0 = blockIdx.x * 128;

  int row = r0 + w * 16 + lr;
  int rc = row < NN ? row : NN - 1;
  const u16* Ap = &z3[(size_t)rc * 256];
  short8 a[8];
#pragma unroll
  for (int ks = 0; ks < 8; ++ks)
    a[ks] = *(const short8*)&Ap[(ks * 4 + lq) * 8];

  {
    const short8* Bv = (const short8*)Wft;
    short8* Bl = (short8*)Bs;
#pragma unroll
    for (int i = 0; i < 3; ++i)
      Bl[tid + i * 512] = Bv[tid + i * 512];
  }
  if (tid < 256) {
    float m = icsum[tid] * (1.0f / NN);
    float var = icsq[tid] * (1.0f / NN) - m * m;
    float s = g[tid] * rsqrtf(var + BN_EPS);
    Tb[tid] = make_float2(s, be[tid] - m * s);
  }
  __syncthreads();

  f32x4 acc[3];
#pragma unroll
  for (int ni = 0; ni < 3; ++ni) acc[ni] = (f32x4){0.f, 0.f, 0.f, 0.f};
#pragma unroll
  for (int ks = 0; ks < 8; ++ks) {
    short8 t0 = a[ks];
    int kb = (ks * 4 + lq) * 8;
#pragma unroll
    for (int j = 0; j < 8; ++j) {
      float2 tb = Tb[kb + j];
      float f0 = fmaxf(fmaf(__uint_as_float(((u32)(u16)t0[j]) << 16), tb.x, tb.y), 0.f);
      t0[j] = (short)f2bf(f0);
    }
#pragma unroll
    for (int ni = 0; ni < 3; ++ni) {
      int col = ni * 16 + lr;
      short8 bfr = *(const short8*)&Bs[(size_t)col * 256 + (((ks * 4 + lq) ^ (col & 7)) << 3)];
      acc[ni] = __builtin_amdgcn_mfma_f32_16x16x32_bf16(t0, bfr, acc[ni], 0, 0, 0);
    }
  }

#pragma unroll
  for (int ni = 0; ni < 3; ++ni) {
    int col = ni * 16 + lr;
    if (col < CDIM) {
      float bfv = bfp[col];
#pragma unroll
      for (int j = 0; j < 4; ++j) {
        int gr = r0 + w * 16 + lq * 4 + j;
        if (gr < NN) out[(size_t)gr * CDIM + col] = acc[ni][j] + bfv;
      }
    }
  }
}

// ---------------- launch ----------------
extern "C" void kernel_launch(void* const* d_in, const int* in_sizes, int n_in,
                              void* d_out, int out_size, void* d_ws, size_t ws_size,
                              hipStream_t stream) {
  const float* x   = (const float*)d_in[0];
  const int*   ei  = (const int*)d_in[1];
  const float* eps1= (const float*)d_in[2];
  const float* W1  = (const float*)d_in[3];
  const float* b1  = (const float*)d_in[4];
  const float* g1  = (const float*)d_in[5];
  const float* be1 = (const float*)d_in[6];
  const float* W2  = (const float*)d_in[7];
  const float* b2  = (const float*)d_in[8];
  const float* eps2= (const float*)d_in[9];
  const float* W3  = (const float*)d_in[10];
  const float* b3  = (const float*)d_in[11];
  const float* g2  = (const float*)d_in[12];
  const float* be2 = (const float*)d_in[13];
  const float* W4  = (const float*)d_in[14];
  const float* b4  = (const float*)d_in[15];
  const float* g3  = (const float*)d_in[16];
  const float* be3 = (const float*)d_in[17];
  const float* Wf  = (const float*)d_in[18];
  const float* bf  = (const float*)d_in[19];
  float* out = (float*)d_out;

  char* p = (char*)d_ws;
  auto alloc = [&](size_t bytes) -> char* {
    char* r = p;
    p += (bytes + 255) & ~(size_t)255;
    return r;
  };
  float* stats   = (float*)alloc(6 * 256 * sizeof(float));  // s1,q1,s2,q2,s3,q3
  int* deg       = (int*)alloc(NN * sizeof(int));
  int* rowstart  = (int*)alloc((NN + 16) * sizeof(int));
  int* cursor    = (int*)alloc(NN * sizeof(int));
  int* sorted    = (int*)alloc(EE * sizeof(int));
  int* partial   = (int*)alloc(NN * sizeof(int));
  int* bsums     = (int*)alloc(1024 * sizeof(int));
  u16* W1t       = (u16*)alloc(256 * 128 * sizeof(u16));
  u16* W2t       = (u16*)alloc(256 * 256 * sizeof(u16));
  u16* W3t       = (u16*)alloc(256 * 256 * sizeof(u16));
  u16* W4t       = (u16*)alloc(256 * 256 * sizeof(u16));
  u16* Wft       = (u16*)alloc(48 * 256 * sizeof(u16));
  u16* xb        = (u16*)alloc((size_t)NN * 128 * sizeof(u16));
  u16* A1        = (u16*)alloc((size_t)NN * 128 * sizeof(u16));
  u16* z1        = (u16*)alloc((size_t)NN * 256 * sizeof(u16));
  u16* h1        = (u16*)alloc((size_t)NN * 256 * sizeof(u16));
  u16* A2        = (u16*)alloc((size_t)NN * 256 * sizeof(u16));
  (void)alloc(64 * 1024);  // guard pad for clamped OOB-adjacent reads
  u16* z2 = z1;  // z1 dead after g2
  u16* z3 = h1;  // h1 dead after agg2

  float* s1 = stats + 0,    *q1 = stats + 256;
  float* s2 = stats + 512,  *q2 = stats + 768;
  float* s3 = stats + 1024, *q3 = stats + 1280;

  const int nbE = (EE + 255) / 256;   // 3125
  const int nbN = (NN + 255) / 256;   // 196

  // prework (cvt_x also zeroes deg & stats; runs before hist)
  k_cvt_x<<<(NN * FDIM / 4 + 255) / 256, 256, 0, stream>>>(x, xb, deg, stats);
  k_cvt_w<<<944, 256, 0, stream>>>(W1, W2, W3, W4, Wf, W1t, W2t, W3t, W4t, Wft);
  k_hist<<<nbE, 256, 0, stream>>>(ei, deg);
  k_scan_blocks<<<nbN, 256, 0, stream>>>(deg, partial, bsums, NN);
  k_scan_sums<<<1, 256, 0, stream>>>(bsums, nbN);
  k_scan_add<<<nbN, 256, 0, stream>>>(partial, bsums, deg, rowstart, cursor, NN);
  k_scatter<<<nbE, 256, 0, stream>>>(ei, cursor, sorted);

  const int gGemm = (NN + 63) / 64;   // 782

  // conv1
  k_agg<128><<<(NN + 3) / 4, 256, 0, stream>>>(xb, rowstart, sorted, eps1, A1);
  k_gemm<128, false, false, true><<<gGemm, 512, 0, stream>>>(
      A1, W1t, b1, nullptr, nullptr, nullptr, nullptr, z1, s1, q1);
  k_gemm<256, true, true, false><<<gGemm, 512, 0, stream>>>(
      z1, W2t, b2, s1, q1, g1, be1, h1, nullptr, nullptr);

  // conv2
  k_agg<256><<<(NN + 3) / 4, 256, 0, stream>>>(h1, rowstart, sorted, eps2, A2);
  k_gemm<256, false, false, true><<<gGemm, 512, 0, stream>>>(
      A2, W3t, b3, nullptr, nullptr, nullptr, nullptr, z2, s2, q2);
  k_gemm<256, true, false, true><<<gGemm, 512, 0, stream>>>(
      z2, W4t, b4, s2, q2, g2, be2, z3, s3, q3);

  // final
  k_final<<<(NN + 127) / 128, 512, 0, stream>>>(z3, Wft, bf, s3, q3, g3, be3, out);
}